// Round 1
// 329.120 us; speedup vs baseline: 1.0551x; 1.0551x over previous
//
#include <hip/hip_runtime.h>
#include <hip/hip_bf16.h>
#include <math.h>

#define N_USERS 100000
#define N_ITEMS 50000
#define N_EDGES 2000000
#define D 64

// Coarse bins: 512 nodes per bin.
#define FB_BINS 98                    // ceil(50000/512)  forward (by item)
#define BB_BINS 196                   // ceil(100000/512) backward (by user)
#define NBINS   (FB_BINS + BB_BINS)   // 294
#define CHUNK   2048                  // edges per binfill WG
#define NCHUNK  ((N_EDGES + CHUNK - 1) / CHUNK)   // 977
// XCD-locality padding: bin counts rounded up to a multiple of 8 so that
// B = blockIdx % PAD puts all 8 sub-WGs of a bin on the same XCD
// (XCD = blockIdx % 8 round-robin; PAD % 8 == 0 => blockIdx % 8 == B % 8).
// Per-XCD stage working set: fwd 13 bins * 82KB ~= 1.07 MB, bwd 25 bins *
// 41KB ~= 1.0 MB -> L2-resident (4 MB/XCD), so the 8 sub-WG x 2-pass scans
// hit L2 instead of refetching from HBM 16x.
#define FB_PAD 104
#define BB_PAD 200
#define FWD_WGS (8 * FB_PAD)          // 832
#define BWD_WGS (8 * BB_PAD)          // 1600
#define CAP     4032                  // LDS sorted-list capacity (mean 2558, sd ~51)

// ---- bf16 pack/unpack helpers --------------------------------------------
__device__ __forceinline__ float blo(unsigned u) {
    union { unsigned i; float f; } c; c.i = u << 16; return c.f;
}
__device__ __forceinline__ float bhi(unsigned u) {
    union { unsigned i; float f; } c; c.i = u & 0xFFFF0000u; return c.f;
}
__device__ __forceinline__ unsigned bpack(float x, float y) {
    __hip_bfloat16 a = __float2bfloat16(x), b = __float2bfloat16(y);
    unsigned short ua = *reinterpret_cast<unsigned short*>(&a);
    unsigned short ub = *reinterpret_cast<unsigned short*>(&b);
    return (unsigned)ua | ((unsigned)ub << 16);
}

// ---------------------------------------------------------------------------
// Convert h_user fp32 -> packed bf16 pairs (hu16): one uint = features 2q,2q+1.
// ---------------------------------------------------------------------------
__global__ __launch_bounds__(256) void h2b_kernel(
    const float2* __restrict__ in, unsigned* __restrict__ out, int n) {
    int stride = gridDim.x * blockDim.x;
    for (int i = blockIdx.x * blockDim.x + threadIdx.x; i < n; i += stride) {
        float2 v = in[i];
        out[i] = bpack(v.x, v.y);
    }
}

// ---------------------------------------------------------------------------
// Histogram of coarse-bin sizes (294 bins, LDS-staged).
// ---------------------------------------------------------------------------
__global__ __launch_bounds__(256) void hist_kernel(
    const int* __restrict__ src, const int* __restrict__ dst, int* __restrict__ gh) {
    __shared__ int h[NBINS];
    for (int i = threadIdx.x; i < NBINS; i += 256) h[i] = 0;
    __syncthreads();
    int stride = gridDim.x * blockDim.x;
    for (int e = blockIdx.x * blockDim.x + threadIdx.x; e < N_EDGES; e += stride) {
        atomicAdd(&h[dst[e] >> 9], 1);
        atomicAdd(&h[FB_BINS + (src[e] >> 9)], 1);
    }
    __syncthreads();
    for (int i = threadIdx.x; i < NBINS; i += 256) {
        int v = h[i];
        if (v) atomicAdd(&gh[i], v);
    }
}

// ---------------------------------------------------------------------------
// Single-block exclusive scan; also initializes the running cursor array.
// ---------------------------------------------------------------------------
__global__ void scan_excl(const int* __restrict__ in, int* __restrict__ out,
                          int* __restrict__ cur, int n) {
    const int T = 1024, E = 4;
    __shared__ int wsum[16];
    __shared__ int s_carry;
    if (threadIdx.x == 0) s_carry = 0;
    __syncthreads();

    int lane = threadIdx.x & 63;
    int wid  = threadIdx.x >> 6;

    for (int base = 0; base < n; base += T * E) {
        int idx0 = base + threadIdx.x * E;
        int v[E];
        int tot = 0;
#pragma unroll
        for (int e = 0; e < E; e++) {
            int i = idx0 + e;
            v[e] = (i < n) ? in[i] : 0;
            tot += v[e];
        }
        int incl = tot;
#pragma unroll
        for (int off = 1; off < 64; off <<= 1) {
            int t = __shfl_up(incl, off);
            if (lane >= off) incl += t;
        }
        if (lane == 63) wsum[wid] = incl;
        __syncthreads();
        if (wid == 0 && lane < 16) {
            int t = wsum[lane];
            int sc = t;
#pragma unroll
            for (int off = 1; off < 16; off <<= 1) {
                int u = __shfl_up(sc, off);
                if (lane >= off) sc += u;
            }
            wsum[lane] = sc - t;
        }
        __syncthreads();
        int wave_off = wsum[wid];
        int excl = s_carry + wave_off + incl - tot;
#pragma unroll
        for (int e = 0; e < E; e++) {
            int i = idx0 + e;
            if (i < n) { out[i] = excl; cur[i] = excl; }
            excl += v[e];
        }
        __syncthreads();
        if (threadIdx.x == T - 1) s_carry += wave_off + incl;
        __syncthreads();
    }
    if (threadIdx.x == 0) out[n] = s_carry;
}

// ---------------------------------------------------------------------------
// binfill: chunk-aggregated scatter (dense ~56 B runs per (chunk,bin)).
// fwd entry: s(17b) | d_local9<<17 ; bwd entry: d(16b) | s_local9<<16.
// ---------------------------------------------------------------------------
__global__ __launch_bounds__(256) void binfill_kernel(
    const int* __restrict__ src, const int* __restrict__ dst,
    int* __restrict__ gcur, unsigned* __restrict__ stage) {
    __shared__ int cnt[NBINS];
    __shared__ int gbase[NBINS];
    __shared__ int lcur[NBINS];
    int c = blockIdx.x;
    int base = c * CHUNK;
    int nEdge = N_EDGES - base; if (nEdge > CHUNK) nEdge = CHUNK;

    for (int t = threadIdx.x; t < NBINS; t += 256) { cnt[t] = 0; lcur[t] = 0; }
    __syncthreads();

    int es[8], ed[8];
#pragma unroll
    for (int j = 0; j < 8; j++) {
        int k = j * 256 + threadIdx.x;
        if (k < nEdge) {
            es[j] = src[base + k];
            ed[j] = dst[base + k];
            atomicAdd(&cnt[ed[j] >> 9], 1);
            atomicAdd(&cnt[FB_BINS + (es[j] >> 9)], 1);
        } else {
            es[j] = -1;
        }
    }
    __syncthreads();
    for (int t = threadIdx.x; t < NBINS; t += 256) {
        int cv = cnt[t];
        gbase[t] = cv ? atomicAdd(&gcur[t], cv) : 0;
    }
    __syncthreads();
#pragma unroll
    for (int j = 0; j < 8; j++) {
        if (es[j] >= 0) {
            int s = es[j], d = ed[j];
            int bf = d >> 9;
            int p = atomicAdd(&lcur[bf], 1);
            stage[gbase[bf] + p] = (unsigned)s | ((unsigned)(d & 511) << 17);
            int bb = FB_BINS + (s >> 9);
            int q = atomicAdd(&lcur[bb], 1);
            stage[gbase[bb] + q] = (unsigned)d | ((unsigned)(s & 511) << 16);
        }
    }
}

// ---------------------------------------------------------------------------
// Global softmax stats over edge_w[N_ITEMS]: stats[0]=max, stats[1]=sum(exp(x-max))
// ---------------------------------------------------------------------------
__global__ void softmax_stats_kernel(const float* __restrict__ w, float* __restrict__ stats) {
    __shared__ float red[16];
    int tid = threadIdx.x, lane = tid & 63, wid = tid >> 6;

    float m = -INFINITY;
    for (int i = tid; i < N_ITEMS; i += 1024) m = fmaxf(m, w[i]);
#pragma unroll
    for (int off = 32; off; off >>= 1) m = fmaxf(m, __shfl_xor(m, off));
    if (lane == 0) red[wid] = m;
    __syncthreads();
    if (tid == 0) {
        float t = red[0];
        for (int k = 1; k < 16; k++) t = fmaxf(t, red[k]);
        red[0] = t;
    }
    __syncthreads();
    m = red[0];
    __syncthreads();

    float s = 0.f;
    for (int i = tid; i < N_ITEMS; i += 1024) s += expf(w[i] - m);
#pragma unroll
    for (int off = 32; off; off >>= 1) s += __shfl_xor(s, off);
    if (lane == 0) red[wid] = s;
    __syncthreads();
    if (tid == 0) {
        float t = 0.f;
        for (int k = 0; k < 16; k++) t += red[k];
        stats[0] = m;
        stats[1] = t;
    }
}

// ---------------------------------------------------------------------------
// pass2 fwd: one 512-thread WG per 64 items. Counting-sort parent-bin edges
// into LDS, then 8 waves gather bf16 h_user rows: 2 edges/wave-load (half-wave
// per edge, uint = 2 bf16 features per lane), register accumulation, fused
// epilogue, bf16 rst output.
// blockIdx -> (B = x % FB_PAD, sub = x / FB_PAD): all 8 sub-WGs of coarse bin
// B land on XCD B%8, so the 16 scans of the bin (8 subs x 2 passes) are
// served by that XCD's L2 after the first touch.
// ---------------------------------------------------------------------------
__global__ __launch_bounds__(512) void pass2_fwd_kernel(
    const unsigned* __restrict__ hu16, const float* __restrict__ pf,
    const float* __restrict__ edge_w, const unsigned* __restrict__ stage,
    const int* __restrict__ binoff, const float* __restrict__ stats,
    unsigned* __restrict__ rst16) {
    __shared__ int cnt[64];
    __shared__ int loc[65];
    __shared__ int lcur[64];
    __shared__ int sorted[CAP];
    int x = blockIdx.x;
    int B = x % FB_PAD, sub = x / FB_PAD;
    if (B >= FB_BINS) return;
    int r = B * 8 + sub;                  // item-group id: items r*64 .. r*64+63
    int beg = binoff[B], end = binoff[B + 1];
    int tid = threadIdx.x, lane = tid & 63, wv = tid >> 6;
    int q = lane & 31, half = lane >> 5;

    if (tid < 64) { cnt[tid] = 0; lcur[tid] = 0; }
    __syncthreads();

    for (int k = beg + tid; k < end; k += 512) {
        unsigned e = stage[k];
        if ((int)(e >> 23) == sub) atomicAdd(&cnt[(e >> 17) & 63], 1);
    }
    __syncthreads();
    if (tid < 64) {   // wave 0: exclusive scan of 64 counts
        int v = cnt[tid];
        int incl = v;
#pragma unroll
        for (int off = 1; off < 64; off <<= 1) {
            int t = __shfl_up(incl, off);
            if (tid >= off) incl += t;
        }
        loc[tid] = incl - v;
        if (tid == 63) loc[64] = incl;
    }
    __syncthreads();
    int nf = loc[64];

    float m = stats[0], ssum = stats[1];
    const float2* PF2 = (const float2*)pf;

    if (nf <= CAP) {
        for (int k = beg + tid; k < end; k += 512) {
            unsigned e = stage[k];
            if ((int)(e >> 23) == sub) {
                int il = (e >> 17) & 63;
                int p = atomicAdd(&lcur[il], 1);
                sorted[loc[il] + p] = (int)(e & 0x1FFFFu);
            }
        }
        __syncthreads();
        for (int il = wv; il < 64; il += 8) {
            int i = r * 64 + il;
            if (i >= N_ITEMS) continue;
            int a = loc[il], b = loc[il + 1];
            float ax = 0.f, ay = 0.f;
            int k = a;
            for (; k + 8 <= b; k += 8) {
                int s0 = sorted[k + half],     s1 = sorted[k + 2 + half];
                int s2 = sorted[k + 4 + half], s3 = sorted[k + 6 + half];
                unsigned u0 = hu16[(s0 << 5) + q];
                unsigned u1 = hu16[(s1 << 5) + q];
                unsigned u2 = hu16[(s2 << 5) + q];
                unsigned u3 = hu16[(s3 << 5) + q];
                ax += (blo(u0) + blo(u1)) + (blo(u2) + blo(u3));
                ay += (bhi(u0) + bhi(u1)) + (bhi(u2) + bhi(u3));
            }
            for (; k + 2 <= b; k += 2) {
                unsigned u = hu16[(sorted[k + half] << 5) + q];
                ax += blo(u); ay += bhi(u);
            }
            if (k < b && half == 0) {
                unsigned u = hu16[(sorted[k] << 5) + q];
                ax += blo(u); ay += bhi(u);
            }
            ax += __shfl_xor(ax, 32);
            ay += __shfl_xor(ay, 32);
            if (half == 0) {
                float deg = (float)(b - a);
                if (deg < 1.f) deg = 1.f;
                float sc = expf(edge_w[i] - m) / (ssum * deg);
                float2 pv = PF2[(size_t)i * 32 + q];
                float vx = (ax + 0.5f * tanhf(pv.x)) * sc;
                float vy = (ay + 0.5f * tanhf(pv.y)) * sc;
                rst16[(size_t)i * 32 + q] = bpack(vx, vy);
            }
        }
    } else {
        // overflow fallback (statistically unreachable): per-item scan of bin
        const unsigned short* HU = (const unsigned short*)hu16;
        for (int il = wv; il < 64; il += 8) {
            int i = r * 64 + il;
            if (i >= N_ITEMS) continue;
            unsigned want = ((unsigned)sub << 6) | (unsigned)il;
            float acc = 0.f;
            int dcount = 0;
            for (int k = beg; k < end; k++) {
                unsigned e = stage[k];
                if ((e >> 17) == want) {
                    union { unsigned u; float f; } c;
                    c.u = (unsigned)HU[(size_t)(e & 0x1FFFFu) * 64 + lane] << 16;
                    acc += c.f; dcount++;
                }
            }
            float deg = (float)dcount;
            if (deg < 1.f) deg = 1.f;
            float sc = expf(edge_w[i] - m) / (ssum * deg);
            float val = (acc + 0.5f * tanhf(pf[(size_t)i * D + lane])) * sc;
            float va = __shfl(val, 2 * q);
            float vb = __shfl(val, 2 * q + 1);
            if (half == 0) rst16[(size_t)i * 32 + q] = bpack(va, vb);
        }
    }
}

// ---------------------------------------------------------------------------
// pass2 bwd: one 512-thread WG per 64 users; same plan over bf16 rst.
// Same XCD-locality remap over the 196 backward coarse bins (pad 200).
// ---------------------------------------------------------------------------
__global__ __launch_bounds__(512) void pass2_bwd_kernel(
    const unsigned* __restrict__ rst16, const unsigned* __restrict__ stage,
    const int* __restrict__ binoff, float* __restrict__ out) {
    __shared__ int cnt[64];
    __shared__ int loc[65];
    __shared__ int lcur[64];
    __shared__ int sorted[CAP];
    int x = blockIdx.x;
    int Bl = x % BB_PAD, sub = x / BB_PAD;
    if (Bl >= BB_BINS) return;
    int B = FB_BINS + Bl;
    int r = Bl * 8 + sub;                 // user-group id: users r*64 .. r*64+63
    int beg = binoff[B], end = binoff[B + 1];
    int tid = threadIdx.x, lane = tid & 63, wv = tid >> 6;
    int q = lane & 31, half = lane >> 5;

    if (tid < 64) { cnt[tid] = 0; lcur[tid] = 0; }
    __syncthreads();

    for (int k = beg + tid; k < end; k += 512) {
        unsigned e = stage[k];
        if ((int)(e >> 22) == sub) atomicAdd(&cnt[(e >> 16) & 63], 1);
    }
    __syncthreads();
    if (tid < 64) {
        int v = cnt[tid];
        int incl = v;
#pragma unroll
        for (int off = 1; off < 64; off <<= 1) {
            int t = __shfl_up(incl, off);
            if (tid >= off) incl += t;
        }
        loc[tid] = incl - v;
        if (tid == 63) loc[64] = incl;
    }
    __syncthreads();
    int nf = loc[64];

    float2* OUT2 = (float2*)out;

    if (nf <= CAP) {
        for (int k = beg + tid; k < end; k += 512) {
            unsigned e = stage[k];
            if ((int)(e >> 22) == sub) {
                int il = (e >> 16) & 63;
                int p = atomicAdd(&lcur[il], 1);
                sorted[loc[il] + p] = (int)(e & 0xFFFFu);
            }
        }
        __syncthreads();
        for (int il = wv; il < 64; il += 8) {
            int u = r * 64 + il;
            if (u >= N_USERS) continue;
            int a = loc[il], b = loc[il + 1];
            float ax = 0.f, ay = 0.f;
            int k = a;
            for (; k + 8 <= b; k += 8) {
                int d0 = sorted[k + half],     d1 = sorted[k + 2 + half];
                int d2 = sorted[k + 4 + half], d3 = sorted[k + 6 + half];
                unsigned u0 = rst16[(d0 << 5) + q];
                unsigned u1 = rst16[(d1 << 5) + q];
                unsigned u2 = rst16[(d2 << 5) + q];
                unsigned u3 = rst16[(d3 << 5) + q];
                ax += (blo(u0) + blo(u1)) + (blo(u2) + blo(u3));
                ay += (bhi(u0) + bhi(u1)) + (bhi(u2) + bhi(u3));
            }
            for (; k + 2 <= b; k += 2) {
                unsigned e = rst16[(sorted[k + half] << 5) + q];
                ax += blo(e); ay += bhi(e);
            }
            if (k < b && half == 0) {
                unsigned e = rst16[(sorted[k] << 5) + q];
                ax += blo(e); ay += bhi(e);
            }
            ax += __shfl_xor(ax, 32);
            ay += __shfl_xor(ay, 32);
            if (half == 0) {
                float deg = (float)(b - a);
                if (deg < 1.f) deg = 1.f;
                OUT2[(size_t)u * 32 + q] = make_float2(ax / deg, ay / deg);
            }
        }
    } else {
        const unsigned short* RS = (const unsigned short*)rst16;
        for (int il = wv; il < 64; il += 8) {
            int u = r * 64 + il;
            if (u >= N_USERS) continue;
            unsigned want = ((unsigned)sub << 6) | (unsigned)il;
            float acc = 0.f;
            int dcount = 0;
            for (int k = beg; k < end; k++) {
                unsigned e = stage[k];
                if ((e >> 16) == want) {
                    union { unsigned ui; float f; } c;
                    c.ui = (unsigned)RS[(size_t)(e & 0xFFFFu) * 64 + lane] << 16;
                    acc += c.f; dcount++;
                }
            }
            float deg = (float)dcount;
            if (deg < 1.f) deg = 1.f;
            out[(size_t)u * D + lane] = acc / deg;
        }
    }
}

// ---------------------------------------------------------------------------
extern "C" void kernel_launch(void* const* d_in, const int* in_sizes, int n_in,
                              void* d_out, int out_size, void* d_ws, size_t ws_size,
                              hipStream_t stream) {
    const float* h_user = (const float*)d_in[0];   // [N_USERS, D]
    const float* pf     = (const float*)d_in[1];   // [N_ITEMS, D]
    const float* edge_w = (const float*)d_in[2];   // [N_ITEMS]
    const int*   src    = (const int*)d_in[3];     // [N_EDGES]
    const int*   dst    = (const int*)d_in[4];     // [N_EDGES]
    float* out = (float*)d_out;                    // [N_USERS, D]

    // workspace carve-up (~35.3 MB)
    char* p = (char*)d_ws;
    int* gh     = (int*)p;      p += sizeof(int) * NBINS;
    int* binoff = (int*)p;      p += sizeof(int) * (NBINS + 1);
    int* gcur   = (int*)p;      p += sizeof(int) * NBINS;
    unsigned* stage = (unsigned*)p; p += sizeof(unsigned) * (size_t)2 * N_EDGES;
    unsigned* hu16  = (unsigned*)p; p += sizeof(unsigned) * (size_t)N_USERS * 32;
    unsigned* rst16 = (unsigned*)p; p += sizeof(unsigned) * (size_t)N_ITEMS * 32;
    float* stats = (float*)p;   p += 2 * sizeof(float);

    hipMemsetAsync(gh, 0, sizeof(int) * NBINS, stream);

    hist_kernel<<<256, 256, 0, stream>>>(src, dst, gh);
    scan_excl<<<1, 1024, 0, stream>>>(gh, binoff, gcur, NBINS);
    binfill_kernel<<<NCHUNK, 256, 0, stream>>>(src, dst, gcur, stage);
    h2b_kernel<<<1024, 256, 0, stream>>>((const float2*)h_user, hu16, N_USERS * 32);
    softmax_stats_kernel<<<1, 1024, 0, stream>>>(edge_w, stats);
    pass2_fwd_kernel<<<FWD_WGS, 512, 0, stream>>>(hu16, pf, edge_w, stage, binoff, stats, rst16);
    pass2_bwd_kernel<<<BWD_WGS, 512, 0, stream>>>(rst16, stage, binoff, out);
}